// Round 5
// baseline (3552.454 us; speedup 1.0000x reference)
//
#include <hip/hip_runtime.h>
#include <hip/hip_fp16.h>

// ---------------------------------------------------------------------------
// HierarchicalVQ round 9.
// proj: 8x8 per-thread tiles (128x128 block) — numerically PROVEN by round-8's
//       first-run pass (all idx exact) — but with round-7's thrice-validated
//       synchronization structure restored: global loads at tile top ->
//       barrier -> LDS write -> barrier -> compute. Round-8's register
//       double-buffer prefetch (loads issued past the second barrier) was the
//       only structural delta in its replay-instability (post-timing output
//       divergence) and is REMOVED. Accumulation order / epilogue bit-identical
//       to validated rounds 4/7: one fp64 acc per output, k ascending,
//       (float)(acc + (double)bias).
// vq:   UNCHANGED fused screen(bf16 MFMA) + fp64 rescue (validated).
// out:  UNCHANGED bf16 MFMA gather-GEMM (validated).
// ---------------------------------------------------------------------------

#define NTOK 65536
#define DIM 512
#define NDIM3 1536

typedef __attribute__((ext_vector_type(8))) short short8;
typedef __attribute__((ext_vector_type(4))) float float4v;

static __device__ __forceinline__ ushort f2bf(float x) {   // fp32 -> bf16 RN
    uint u = __float_as_uint(x);
    uint r = u + 0x7FFFu + ((u >> 16) & 1u);
    return (ushort)(r >> 16);
}

// ======================= proj: fp64 VALU GEMM, 8x8 tiles ===================
#define PBM 128
#define PBN 128
#define PBK 16
#define PRS 160   // doubles per k-row: 16 chunks * 10 (8 data + 2 pad)

__global__ __launch_bounds__(256, 2)
void proj_kernel(const float* __restrict__ X, const float* __restrict__ W,
                 const float* __restrict__ bias, float* __restrict__ out) {
    __shared__ __align__(16) double As[PBK][PRS];   // [k][chunkpos(row)]
    __shared__ __align__(16) double Bs[PBK][PRS];   // [k][chunkpos(col)]

    const int tid = threadIdx.x;
    const int tx = tid & 15, ty = tid >> 4;         // col-chunk, row-chunk
    const int row0 = blockIdx.x * PBM;
    const int col0 = blockIdx.y * PBN;

    // staging: thread loads 8 consecutive k of one A row and one B row
    const int sr  = tid >> 1, skq = (tid & 1) * 8;
    const int spos = (sr >> 3) * 10 + (sr & 7);     // chunk-swizzled position

    const float* Xp = X + (size_t)(row0 + sr) * DIM + skq;
    const float* Wp = W + (size_t)(col0 + sr) * DIM + skq;

    double acc[8][8];
#pragma unroll
    for (int r = 0; r < 8; ++r)
#pragma unroll
        for (int c = 0; c < 8; ++c) acc[r][c] = 0.0;

    for (int k0 = 0; k0 < DIM; k0 += PBK) {
        // loads at tile top (validated round-7 structure; no cross-barrier
        // register pipelining)
        float4 ax0 = *(const float4*)(Xp + k0);
        float4 ax1 = *(const float4*)(Xp + k0 + 4);
        float4 bx0 = *(const float4*)(Wp + k0);
        float4 bx1 = *(const float4*)(Wp + k0 + 4);
        __syncthreads();
        As[skq + 0][spos] = (double)ax0.x;
        As[skq + 1][spos] = (double)ax0.y;
        As[skq + 2][spos] = (double)ax0.z;
        As[skq + 3][spos] = (double)ax0.w;
        As[skq + 4][spos] = (double)ax1.x;
        As[skq + 5][spos] = (double)ax1.y;
        As[skq + 6][spos] = (double)ax1.z;
        As[skq + 7][spos] = (double)ax1.w;
        Bs[skq + 0][spos] = (double)bx0.x;
        Bs[skq + 1][spos] = (double)bx0.y;
        Bs[skq + 2][spos] = (double)bx0.z;
        Bs[skq + 3][spos] = (double)bx0.w;
        Bs[skq + 4][spos] = (double)bx1.x;
        Bs[skq + 5][spos] = (double)bx1.y;
        Bs[skq + 6][spos] = (double)bx1.z;
        Bs[skq + 7][spos] = (double)bx1.w;
        __syncthreads();
#pragma unroll
        for (int kk = 0; kk < PBK; ++kk) {
            double a[8], b[8];
#pragma unroll
            for (int r = 0; r < 8; ++r) a[r] = As[kk][ty * 10 + r];
#pragma unroll
            for (int c = 0; c < 8; ++c) b[c] = Bs[kk][tx * 10 + c];
#pragma unroll
            for (int r = 0; r < 8; ++r)
#pragma unroll
                for (int c = 0; c < 8; ++c)
                    acc[r][c] += a[r] * b[c];
        }
    }
    double bcol[8];
#pragma unroll
    for (int c = 0; c < 8; ++c) bcol[c] = (double)bias[col0 + tx * 8 + c];
#pragma unroll
    for (int r = 0; r < 8; ++r) {
        const int row = row0 + ty * 8 + r;
        float4 o0, o1;
        o0.x = (float)(acc[r][0] + bcol[0]); o0.y = (float)(acc[r][1] + bcol[1]);
        o0.z = (float)(acc[r][2] + bcol[2]); o0.w = (float)(acc[r][3] + bcol[3]);
        o1.x = (float)(acc[r][4] + bcol[4]); o1.y = (float)(acc[r][5] + bcol[5]);
        o1.z = (float)(acc[r][6] + bcol[6]); o1.w = (float)(acc[r][7] + bcol[7]);
        *(float4*)(out + (size_t)row * DIM + col0 + tx * 8)     = o0;
        *(float4*)(out + (size_t)row * DIM + col0 + tx * 8 + 4) = o1;
    }
}

// ======================= fused VQ: bf16 screen + fp64 rescue ===============
#define TAU_A 2.0e-3f

template<bool RESID>
__global__ __launch_bounds__(256)
void vq_fused(const float* __restrict__ feat, const float* __restrict__ cb, int K,
              const float* __restrict__ cb_prev, const float* __restrict__ previdx_f,
              float* __restrict__ idx_out, float* __restrict__ loss_acc) {
    __shared__ __align__(16) ushort A_s[64][40];    // [token][k] bf16, ONE k-tile
    __shared__ __align__(16) ushort B_s[256][40];   // [cand][k]  bf16, ONE k-tile
    __shared__ __half Csub[64][264];                // [token][cand-in-tile]
    __shared__ int    sPrev[64];
    __shared__ float  mgMax[64][4];
    __shared__ float  mgVal[64][4][4];
    __shared__ int    mgIdx[64][4][4];
    __shared__ int    jobCnt[64];
    __shared__ int    jobIdx[64][8];

    const int tid  = threadIdx.x;
    const int lane = tid & 63;
    const int wave = tid >> 6;
    const int quad = lane >> 4;
    const int l15  = lane & 15;
    const int row0 = blockIdx.x * 64;

    if (RESID) { if (tid < 64) sPrev[tid] = (int)previdx_f[row0 + tid]; }
    __syncthreads();

    // screening owner state: owner = (token, quarter-of-candidates)
    const int otok = tid >> 2, opart = tid & 3;
    float submax = -3.0e38f;
    float sval[4]; int sidx[4]; int scnt = 0;
#pragma unroll
    for (int s = 0; s < 4; ++s) { sval[s] = -3.0e38f; sidx[s] = 0; }

    const int nct = K >> 8;           // 512 -> 2 tiles, 256 -> 1 tile
    for (int ct = 0; ct < nct; ++ct) {
        float4v acc[4][4];
#pragma unroll
        for (int mt = 0; mt < 4; ++mt)
#pragma unroll
            for (int nt = 0; nt < 4; ++nt) acc[mt][nt] = 0.0f;

        for (int kt = 0; kt < DIM / 32; ++kt) {
            __syncthreads();
            {   // A: re-staged EVERY (ct, kt) — A_s holds only this k-tile
                const int tok = tid >> 2, kk = (tid & 3) * 8;
                const float* src = feat + (size_t)(row0 + tok) * DIM + kt * 32 + kk;
                float4 f0 = *(const float4*)src;
                float4 f1 = *(const float4*)(src + 4);
                if (RESID) {
                    const float* pr = cb_prev + (size_t)sPrev[tok] * DIM + kt * 32 + kk;
                    float4 p0 = *(const float4*)pr;
                    float4 p1 = *(const float4*)(pr + 4);
                    f0.x -= p0.x; f0.y -= p0.y; f0.z -= p0.z; f0.w -= p0.w;
                    f1.x -= p1.x; f1.y -= p1.y; f1.z -= p1.z; f1.w -= p1.w;
                }
                short8 hv;
                hv[0] = (short)f2bf(f0.x); hv[1] = (short)f2bf(f0.y);
                hv[2] = (short)f2bf(f0.z); hv[3] = (short)f2bf(f0.w);
                hv[4] = (short)f2bf(f1.x); hv[5] = (short)f2bf(f1.y);
                hv[6] = (short)f2bf(f1.z); hv[7] = (short)f2bf(f1.w);
                *(short8*)&A_s[tok][kk] = hv;
            }
            {   // B: thread tid stages candidate row tid (32 k's)
                const float* src = cb + (size_t)(ct * 256 + tid) * DIM + kt * 32;
#pragma unroll
                for (int h = 0; h < 4; ++h) {
                    float4 b0 = *(const float4*)(src + h * 8);
                    float4 b1 = *(const float4*)(src + h * 8 + 4);
                    short8 hv;
                    hv[0] = (short)f2bf(b0.x); hv[1] = (short)f2bf(b0.y);
                    hv[2] = (short)f2bf(b0.z); hv[3] = (short)f2bf(b0.w);
                    hv[4] = (short)f2bf(b1.x); hv[5] = (short)f2bf(b1.y);
                    hv[6] = (short)f2bf(b1.z); hv[7] = (short)f2bf(b1.w);
                    *(short8*)&B_s[tid][h * 8] = hv;
                }
            }
            __syncthreads();
            short8 af[4], bf[4];
#pragma unroll
            for (int mt = 0; mt < 4; ++mt)
                af[mt] = *(const short8*)&A_s[mt * 16 + l15][quad * 8];
#pragma unroll
            for (int nt = 0; nt < 4; ++nt)
                bf[nt] = *(const short8*)&B_s[wave * 64 + nt * 16 + l15][quad * 8];
#pragma unroll
            for (int mt = 0; mt < 4; ++mt)
#pragma unroll
                for (int nt = 0; nt < 4; ++nt)
                    acc[mt][nt] = __builtin_amdgcn_mfma_f32_16x16x32_bf16(
                        af[mt], bf[nt], acc[mt][nt], 0, 0, 0);
        }
        // write scores to Csub:  row = token, col = cand-in-tile
        __syncthreads();
#pragma unroll
        for (int mt = 0; mt < 4; ++mt)
#pragma unroll
            for (int nt = 0; nt < 4; ++nt)
#pragma unroll
                for (int r = 0; r < 4; ++r)
                    Csub[mt * 16 + quad * 4 + r][wave * 64 + nt * 16 + l15] =
                        __float2half(acc[mt][nt][r]);
        __syncthreads();
        // streaming top-window scan (owner threads)
        for (int j = 0; j < 64; ++j) {
            const int c = opart * 64 + j;
            const float a = __half2float(Csub[otok][c]);
            if (a > submax) submax = a;
            if (a >= submax - TAU_A) {
                const int gc = ct * 256 + c;
                if (scnt < 4) { sval[scnt] = a; sidx[scnt] = gc; ++scnt; }
                else {
                    int w = 0;
#pragma unroll
                    for (int s = 1; s < 4; ++s) if (sval[s] < sval[w]) w = s;
                    if (a > sval[w]) { sval[w] = a; sidx[w] = gc; }
                }
            }
        }
    }

    // merge the 4 sub-owners of each token into a job list
    mgMax[otok][opart] = submax;
#pragma unroll
    for (int s = 0; s < 4; ++s) {
        mgVal[otok][opart][s] = (s < scnt) ? sval[s] : -3.0e38f;
        mgIdx[otok][opart][s] = sidx[s];
    }
    __syncthreads();
    if (tid < 64) {
        float g = mgMax[tid][0];
#pragma unroll
        for (int p = 1; p < 4; ++p) g = fmaxf(g, mgMax[tid][p]);
        int cnt = 0;
#pragma unroll
        for (int p = 0; p < 4; ++p)
#pragma unroll
            for (int s = 0; s < 4; ++s) {
                const float a = mgVal[tid][p][s];
                if (a >= g - TAU_A && cnt < 8) jobIdx[tid][cnt++] = mgIdx[tid][p][s];
            }
        jobCnt[tid] = cnt;
    }
    __syncthreads();

    // ---- rescue: exact fp64 rescoring with round-2's fp32-grid emulation ----
    double lsum = 0.0;
    for (int t = wave; t < 64; t += 4) {
        const float* fr = feat + (size_t)(row0 + t) * DIM + lane * 8;
        float4 f0 = *(const float4*)fr;
        float4 f1 = *(const float4*)(fr + 4);
        if (RESID) {
            const float* pr = cb_prev + (size_t)sPrev[t] * DIM + lane * 8;
            float4 p0 = *(const float4*)pr;
            float4 p1 = *(const float4*)(pr + 4);
            f0.x -= p0.x; f0.y -= p0.y; f0.z -= p0.z; f0.w -= p0.w;
            f1.x -= p1.x; f1.y -= p1.y; f1.z -= p1.z; f1.w -= p1.w;
        }
        float v[8] = {f0.x, f0.y, f0.z, f0.w, f1.x, f1.y, f1.z, f1.w};
        double vv = 0.0;
#pragma unroll
        for (int u = 0; u < 8; ++u) vv += (double)v[u] * (double)v[u];
        for (int o = 1; o < 64; o <<= 1) vv += __shfl_xor(vv, o, 64);

        float bestd = 3.4e38f; int besti = 0x7fffffff; double bestl = 0.0;
        const int cnt = jobCnt[t];
        for (int j = 0; j < cnt; ++j) {
            const int c = jobIdx[t][j];
            const float* cr = cb + (size_t)c * DIM + lane * 8;
            float4 c0v = *(const float4*)cr;
            float4 c1v = *(const float4*)(cr + 4);
            float cv[8] = {c0v.x, c0v.y, c0v.z, c0v.w, c1v.x, c1v.y, c1v.z, c1v.w};
            double dot = 0.0, cn = 0.0;
#pragma unroll
            for (int u = 0; u < 8; ++u) {
                dot += (double)v[u] * (double)cv[u];
                cn  += (double)cv[u] * (double)cv[u];
            }
            for (int o = 1; o < 64; o <<= 1) {
                dot += __shfl_xor(dot, o, 64);
                cn  += __shfl_xor(cn,  o, 64);
            }
            const float A32 = (float)vv;
            const float d32 = __fsub_rn(__fadd_rn(A32, (float)cn),
                                        __fmul_rn(2.0f, (float)dot));
            if (d32 < bestd || (d32 == bestd && c < besti)) {
                bestd = d32; besti = c; bestl = (vv + cn) - 2.0 * dot;
            }
        }
        if (lane == 0) { idx_out[row0 + t] = (float)besti; lsum += bestl; }
    }
    if (lane == 0) atomicAdd(loss_acc, (float)lsum);
}

// ======================= out: bf16 MFMA gather-GEMM ========================
__global__ __launch_bounds__(256)
void out_kernel(const float* __restrict__ t_cb, const float* __restrict__ e_cb,
                const float* __restrict__ d_cb0, const float* __restrict__ d_cb1,
                const float* __restrict__ W, const float* __restrict__ bias,
                const float* __restrict__ idx_base, float* __restrict__ outq) {
    __shared__ __align__(16) ushort A_s[128][40];
    __shared__ __align__(16) ushort B_s[128][40];
    __shared__ int sIdx[4][128];

    const int tid  = threadIdx.x;
    const int lane = tid & 63;
    const int wave = tid >> 6;
    const int quad = lane >> 4;
    const int l15  = lane & 15;
    const int row0 = blockIdx.x * 128;
    const int col0 = blockIdx.y * 128;
    const int mw = (wave >> 1) * 64, nw = (wave & 1) * 64;

    {
        int e = tid;
        sIdx[e >> 7][e & 127] = (int)idx_base[(size_t)(e >> 7) * NTOK + row0 + (e & 127)];
        e = tid + 256;
        sIdx[e >> 7][e & 127] = (int)idx_base[(size_t)(e >> 7) * NTOK + row0 + (e & 127)];
    }

    float4v acc[4][4];
#pragma unroll
    for (int mt = 0; mt < 4; ++mt)
#pragma unroll
        for (int nt = 0; nt < 4; ++nt) acc[mt][nt] = 0.0f;

    for (int kt = 0; kt < NDIM3 / 32; ++kt) {
        const int k0 = kt * 32;
        const int seg = k0 >> 9;
        __syncthreads();
        {   // A: gathered combined row -> bf16
            const int tok = tid >> 1, kk = (tid & 1) * 16;
            const int off = (k0 & 511) + kk;
            float fv[16];
            if (seg == 0) {
                const float* s = t_cb + (size_t)sIdx[0][tok] * DIM + off;
#pragma unroll
                for (int u = 0; u < 4; ++u) *(float4*)&fv[u * 4] = *(const float4*)(s + u * 4);
            } else if (seg == 1) {
                const float* s = e_cb + (size_t)sIdx[1][tok] * DIM + off;
#pragma unroll
                for (int u = 0; u < 4; ++u) *(float4*)&fv[u * 4] = *(const float4*)(s + u * 4);
            } else {
                const float* s0 = d_cb0 + (size_t)sIdx[2][tok] * DIM + off;
                const float* s1 = d_cb1 + (size_t)sIdx[3][tok] * DIM + off;
#pragma unroll
                for (int u = 0; u < 4; ++u) {
                    float4 a0 = *(const float4*)(s0 + u * 4);
                    float4 a1 = *(const float4*)(s1 + u * 4);
                    fv[u * 4 + 0] = a0.x + a1.x; fv[u * 4 + 1] = a0.y + a1.y;
                    fv[u * 4 + 2] = a0.z + a1.z; fv[u * 4 + 3] = a0.w + a1.w;
                }
            }
#pragma unroll
            for (int h = 0; h < 2; ++h) {
                short8 hv;
#pragma unroll
                for (int u = 0; u < 8; ++u) hv[u] = (short)f2bf(fv[h * 8 + u]);
                *(short8*)&A_s[tok][kk + h * 8] = hv;
            }
        }
        {   // B: out_W rows
            const int col = tid >> 1, kk = (tid & 1) * 16;
            const float* s = W + (size_t)(col0 + col) * NDIM3 + k0 + kk;
#pragma unroll
            for (int h = 0; h < 2; ++h) {
                float4 b0 = *(const float4*)(s + h * 8);
                float4 b1 = *(const float4*)(s + h * 8 + 4);
                short8 hv;
                hv[0] = (short)f2bf(b0.x); hv[1] = (short)f2bf(b0.y);
                hv[2] = (short)f2bf(b0.z); hv[3] = (short)f2bf(b0.w);
                hv[4] = (short)f2bf(b1.x); hv[5] = (short)f2bf(b1.y);
                hv[6] = (short)f2bf(b1.z); hv[7] = (short)f2bf(b1.w);
                *(short8*)&B_s[col][kk + h * 8] = hv;
            }
        }
        __syncthreads();
        short8 af[4], bf[4];
#pragma unroll
        for (int mt = 0; mt < 4; ++mt)
            af[mt] = *(const short8*)&A_s[mw + mt * 16 + l15][quad * 8];
#pragma unroll
        for (int nt = 0; nt < 4; ++nt)
            bf[nt] = *(const short8*)&B_s[nw + nt * 16 + l15][quad * 8];
#pragma unroll
        for (int mt = 0; mt < 4; ++mt)
#pragma unroll
            for (int nt = 0; nt < 4; ++nt)
                acc[mt][nt] = __builtin_amdgcn_mfma_f32_16x16x32_bf16(
                    af[mt], bf[nt], acc[mt][nt], 0, 0, 0);
    }

#pragma unroll
    for (int nt = 0; nt < 4; ++nt) {
        const int col = col0 + nw + nt * 16 + l15;
        const float bc = bias[col];
#pragma unroll
        for (int mt = 0; mt < 4; ++mt) {
            const int row = row0 + mw + mt * 16 + quad * 4;
#pragma unroll
            for (int r = 0; r < 4; ++r)
                outq[(size_t)(row + r) * DIM + col] = acc[mt][nt][r] + bc;
        }
    }
}

// ---------------------------------------------------------------------------
__global__ void init_loss_kernel(float* __restrict__ p) { *p = 0.0f; }

__global__ void finalize_kernel(float* __restrict__ p) {
    *p = 1.25f * (*p) / (float)(NTOK * DIM);
}

// ---------------------------------------------------------------------------
extern "C" void kernel_launch(void* const* d_in, const int* in_sizes, int n_in,
                              void* d_out, int out_size, void* d_ws, size_t ws_size,
                              hipStream_t stream) {
    const float* x    = (const float*)d_in[0];
    const float* tW   = (const float*)d_in[1];
    const float* tb   = (const float*)d_in[2];
    const float* eW   = (const float*)d_in[3];
    const float* eb   = (const float*)d_in[4];
    const float* dW   = (const float*)d_in[5];
    const float* db   = (const float*)d_in[6];
    const float* oW   = (const float*)d_in[7];
    const float* ob   = (const float*)d_in[8];
    const float* t_cb = (const float*)d_in[9];
    const float* e_cb = (const float*)d_in[10];
    const float* c0   = (const float*)d_in[11];
    const float* c1   = (const float*)d_in[12];

    float* out = (float*)d_out;
    float* feat = out;                          // feat scratch, overwritten at end
    float* idx_t = out + (size_t)NTOK * DIM;
    float* idx_e = idx_t + NTOK;
    float* idx_0 = idx_e + NTOK;
    float* idx_1 = idx_0 + NTOK;
    float* loss_out = idx_1 + NTOK;

    const dim3 gproj(NTOK / PBM, DIM / PBN);    // (512, 4)
    const int  gvq = NTOK / 64;                 // 1024
    const dim3 gout(NTOK / 128, DIM / 128);     // (512, 4)

    init_loss_kernel<<<1, 1, 0, stream>>>(loss_out);

    proj_kernel<<<gproj, 256, 0, stream>>>(x, tW, tb, feat);
    vq_fused<false><<<gvq, 256, 0, stream>>>(feat, t_cb, 512, nullptr, nullptr, idx_t, loss_out);

    proj_kernel<<<gproj, 256, 0, stream>>>(x, eW, eb, feat);
    vq_fused<false><<<gvq, 256, 0, stream>>>(feat, e_cb, 256, nullptr, nullptr, idx_e, loss_out);

    proj_kernel<<<gproj, 256, 0, stream>>>(x, dW, db, feat);
    vq_fused<false><<<gvq, 256, 0, stream>>>(feat, c0, 512, nullptr, nullptr, idx_0, loss_out);
    vq_fused<true><<<gvq, 256, 0, stream>>>(feat, c1, 512, c0, idx_0, idx_1, loss_out);

    out_kernel<<<gout, 256, 0, stream>>>(t_cb, e_cb, c0, c1, oW, ob, idx_t, out);
    finalize_kernel<<<1, 1, 0, stream>>>(loss_out);
}

// Round 6
// 3032.910 us; speedup vs baseline: 1.1713x; 1.1713x over previous
//
#include <hip/hip_runtime.h>
#include <hip/hip_fp16.h>

// ---------------------------------------------------------------------------
// HierarchicalVQ round 10.
// proj: f64 MFMA (v_mfma_f64_16x16x4f64) with an IN-KERNEL LAYOUT PROBE.
//       Round-5's f64-MFMA failure was most likely a wrong C/D row mapping
//       (output-0 "pass" was uninformative at threshold 10.24). The probe runs
//       one MFMA on asymmetric integer matrices (exact in fp64) and checks the
//       result against the true product under BOTH candidate D-layouts:
//         L1: row = quad*4 + r      L2: row = quad + 4*r     (col = l15 both)
//       Match -> MFMA path with that layout (matrix pipe does all FMAs, VALU
//       freed for staging; round-7 was VALU/LDS-bound at 795us vs 437us floor).
//       No match -> block-uniform branch to a plain-VALU fp64 4x8 fallback on
//       the same fp32 LDS tiles (correct, just slower). Numerics: MFMA K=4
//       internal order shifts feat by ~1e-16 relative — 1000x below the
//       fp32-accum feat error the validated TAU rescue already tolerates.
//       Sync structure in BOTH paths = thrice-validated load -> barrier ->
//       LDS write -> barrier -> compute. No cross-barrier register pipelining
//       (round-8 lesson). Round-9 lesson: 64-double accumulators force AGPR
//       shuffling (VGPR_Count 88 < 128 needed); MFMA acc lives in AGPRs
//       NATIVELY, so the f64-MFMA path sidesteps that entirely.
// vq:   UNCHANGED fused screen(bf16 MFMA) + fp64 rescue (validated).
// out:  UNCHANGED bf16 MFMA gather-GEMM (validated).
// ---------------------------------------------------------------------------

#define NTOK 65536
#define DIM 512
#define NDIM3 1536

typedef __attribute__((ext_vector_type(8))) short short8;
typedef __attribute__((ext_vector_type(4))) float float4v;
typedef __attribute__((ext_vector_type(4))) double f64x4;

static __device__ __forceinline__ ushort f2bf(float x) {   // fp32 -> bf16 RN
    uint u = __float_as_uint(x);
    uint r = u + 0x7FFFu + ((u >> 16) & 1u);
    return (ushort)(r >> 16);
}

// ======================= proj: f64 MFMA GEMM + probe =======================
// out[r][c] = sum_k X[r][k]*W[c][k] + b[c]; fp64 accumulate, fp32 store.
// Block 64 rows x 128 cols, 4 waves; wave w owns cols [w*32, w*32+32).
#define PBM 64
#define PBN 128

__global__ __launch_bounds__(256, 2)
void proj_kernel(const float* __restrict__ X, const float* __restrict__ W,
                 const float* __restrict__ bias, float* __restrict__ out) {
    __shared__ __align__(16) float As[64][20];    // [row][k] 16k + 4 pad
    __shared__ __align__(16) float Bs[128][20];   // [col][k]

    const int tid  = threadIdx.x;
    const int lane = tid & 63;
    const int wave = tid >> 6;
    const int quad = lane >> 4;
    const int l15  = lane & 15;
    const int row0 = blockIdx.x * PBM;
    const int col0 = blockIdx.y * PBN;
    const int nw   = wave * 32;

    // ---- layout probe: A[i][k]=8i+k+1, B[k][j]=100k+j+1 (exact in fp64) ----
    // Assumed input layouts (mirror validated bf16 kernels):
    //   A-frag: lane holds A[row=l15][k=quad]; B-frag: lane holds B[k=quad][col=l15]
    {
    }
    double a_p = (double)(8 * l15 + quad + 1);
    double b_p = (double)(100 * quad + l15 + 1);
    f64x4 pacc = {0.0, 0.0, 0.0, 0.0};
    pacc = __builtin_amdgcn_mfma_f64_16x16x4f64(a_p, b_p, pacc, 0, 0, 0);
    bool c1 = true, c2 = true;
#pragma unroll
    for (int r = 0; r < 4; ++r) {
        const int i1 = quad * 4 + r;      // L1 candidate row
        const int i2 = quad + 4 * r;      // L2 candidate row
        double d1 = 0.0, d2 = 0.0;
#pragma unroll
        for (int k = 0; k < 4; ++k) {
            d1 += (double)(8 * i1 + k + 1) * (double)(100 * k + l15 + 1);
            d2 += (double)(8 * i2 + k + 1) * (double)(100 * k + l15 + 1);
        }
        c1 = c1 && (pacc[r] == d1);
        c2 = c2 && (pacc[r] == d2);
    }
    const bool m1 = (__all(c1 ? 1 : 0) != 0);   // HW-uniform -> block-uniform
    const bool m2 = (__all(c2 ? 1 : 0) != 0);

    // staging map (both paths): A 64x16 -> 1 float4/thread; B 128x16 -> 2
    const int asr = tid >> 2, askq = (tid & 3) * 4;
    const int bsr = tid >> 1, bskq = (tid & 1) * 8;
    const float* Xp = X + (size_t)(row0 + asr) * DIM + askq;
    const float* Wp = W + (size_t)(col0 + bsr) * DIM + bskq;

    if (m1 || m2) {
        // ---------------- MFMA path ----------------
        f64x4 acc[4][2];
#pragma unroll
        for (int mt = 0; mt < 4; ++mt)
#pragma unroll
            for (int nt = 0; nt < 2; ++nt) acc[mt][nt] = 0.0;

        for (int k0 = 0; k0 < DIM; k0 += 16) {
            float4 av  = *(const float4*)(Xp + k0);
            float4 bv0 = *(const float4*)(Wp + k0);
            float4 bv1 = *(const float4*)(Wp + k0 + 4);
            __syncthreads();
            *(float4*)&As[asr][askq]     = av;
            *(float4*)&Bs[bsr][bskq]     = bv0;
            *(float4*)&Bs[bsr][bskq + 4] = bv1;
            __syncthreads();
#pragma unroll
            for (int ks = 0; ks < 4; ++ks) {
                double a[4], b[2];
#pragma unroll
                for (int mt = 0; mt < 4; ++mt)
                    a[mt] = (double)As[mt * 16 + l15][ks * 4 + quad];
#pragma unroll
                for (int nt = 0; nt < 2; ++nt)
                    b[nt] = (double)Bs[nw + nt * 16 + l15][ks * 4 + quad];
#pragma unroll
                for (int mt = 0; mt < 4; ++mt)
#pragma unroll
                    for (int nt = 0; nt < 2; ++nt)
                        acc[mt][nt] = __builtin_amdgcn_mfma_f64_16x16x4f64(
                            a[mt], b[nt], acc[mt][nt], 0, 0, 0);
            }
        }
        const int rbase = m1 ? (quad * 4) : quad;
        const int rstep = m1 ? 1 : 4;
#pragma unroll
        for (int nt = 0; nt < 2; ++nt) {
            const int col = col0 + nw + nt * 16 + l15;
            const double bc = (double)bias[col];
#pragma unroll
            for (int mt = 0; mt < 4; ++mt)
#pragma unroll
                for (int r = 0; r < 4; ++r) {
                    const int row = row0 + mt * 16 + rbase + r * rstep;
                    out[(size_t)row * DIM + col] = (float)(acc[mt][nt][r] + bc);
                }
        }
    } else {
        // ---------------- VALU fallback (correct-by-construction) ----------
        const int tx = tid & 15, ty = tid >> 4;
        double acc2[4][8];
#pragma unroll
        for (int r = 0; r < 4; ++r)
#pragma unroll
            for (int c = 0; c < 8; ++c) acc2[r][c] = 0.0;

        for (int k0 = 0; k0 < DIM; k0 += 16) {
            float4 av  = *(const float4*)(Xp + k0);
            float4 bv0 = *(const float4*)(Wp + k0);
            float4 bv1 = *(const float4*)(Wp + k0 + 4);
            __syncthreads();
            *(float4*)&As[asr][askq]     = av;
            *(float4*)&Bs[bsr][bskq]     = bv0;
            *(float4*)&Bs[bsr][bskq + 4] = bv1;
            __syncthreads();
#pragma unroll
            for (int kk = 0; kk < 16; ++kk) {
                double a[4], b[8];
#pragma unroll
                for (int r = 0; r < 4; ++r) a[r] = (double)As[ty * 4 + r][kk];
#pragma unroll
                for (int c = 0; c < 8; ++c) b[c] = (double)Bs[tx + 16 * c][kk];
#pragma unroll
                for (int r = 0; r < 4; ++r)
#pragma unroll
                    for (int c = 0; c < 8; ++c)
                        acc2[r][c] += a[r] * b[c];
            }
        }
        double bcol[8];
#pragma unroll
        for (int c = 0; c < 8; ++c) bcol[c] = (double)bias[col0 + tx + 16 * c];
#pragma unroll
        for (int r = 0; r < 4; ++r) {
            const int row = row0 + ty * 4 + r;
#pragma unroll
            for (int c = 0; c < 8; ++c)
                out[(size_t)row * DIM + col0 + tx + 16 * c] =
                    (float)(acc2[r][c] + bcol[c]);
        }
    }
}

// ======================= fused VQ: bf16 screen + fp64 rescue ===============
#define TAU_A 2.0e-3f

template<bool RESID>
__global__ __launch_bounds__(256)
void vq_fused(const float* __restrict__ feat, const float* __restrict__ cb, int K,
              const float* __restrict__ cb_prev, const float* __restrict__ previdx_f,
              float* __restrict__ idx_out, float* __restrict__ loss_acc) {
    __shared__ __align__(16) ushort A_s[64][40];    // [token][k] bf16, ONE k-tile
    __shared__ __align__(16) ushort B_s[256][40];   // [cand][k]  bf16, ONE k-tile
    __shared__ __half Csub[64][264];                // [token][cand-in-tile]
    __shared__ int    sPrev[64];
    __shared__ float  mgMax[64][4];
    __shared__ float  mgVal[64][4][4];
    __shared__ int    mgIdx[64][4][4];
    __shared__ int    jobCnt[64];
    __shared__ int    jobIdx[64][8];

    const int tid  = threadIdx.x;
    const int lane = tid & 63;
    const int wave = tid >> 6;
    const int quad = lane >> 4;
    const int l15  = lane & 15;
    const int row0 = blockIdx.x * 64;

    if (RESID) { if (tid < 64) sPrev[tid] = (int)previdx_f[row0 + tid]; }
    __syncthreads();

    // screening owner state: owner = (token, quarter-of-candidates)
    const int otok = tid >> 2, opart = tid & 3;
    float submax = -3.0e38f;
    float sval[4]; int sidx[4]; int scnt = 0;
#pragma unroll
    for (int s = 0; s < 4; ++s) { sval[s] = -3.0e38f; sidx[s] = 0; }

    const int nct = K >> 8;           // 512 -> 2 tiles, 256 -> 1 tile
    for (int ct = 0; ct < nct; ++ct) {
        float4v acc[4][4];
#pragma unroll
        for (int mt = 0; mt < 4; ++mt)
#pragma unroll
            for (int nt = 0; nt < 4; ++nt) acc[mt][nt] = 0.0f;

        for (int kt = 0; kt < DIM / 32; ++kt) {
            __syncthreads();
            {   // A: re-staged EVERY (ct, kt) — A_s holds only this k-tile
                const int tok = tid >> 2, kk = (tid & 3) * 8;
                const float* src = feat + (size_t)(row0 + tok) * DIM + kt * 32 + kk;
                float4 f0 = *(const float4*)src;
                float4 f1 = *(const float4*)(src + 4);
                if (RESID) {
                    const float* pr = cb_prev + (size_t)sPrev[tok] * DIM + kt * 32 + kk;
                    float4 p0 = *(const float4*)pr;
                    float4 p1 = *(const float4*)(pr + 4);
                    f0.x -= p0.x; f0.y -= p0.y; f0.z -= p0.z; f0.w -= p0.w;
                    f1.x -= p1.x; f1.y -= p1.y; f1.z -= p1.z; f1.w -= p1.w;
                }
                short8 hv;
                hv[0] = (short)f2bf(f0.x); hv[1] = (short)f2bf(f0.y);
                hv[2] = (short)f2bf(f0.z); hv[3] = (short)f2bf(f0.w);
                hv[4] = (short)f2bf(f1.x); hv[5] = (short)f2bf(f1.y);
                hv[6] = (short)f2bf(f1.z); hv[7] = (short)f2bf(f1.w);
                *(short8*)&A_s[tok][kk] = hv;
            }
            {   // B: thread tid stages candidate row tid (32 k's)
                const float* src = cb + (size_t)(ct * 256 + tid) * DIM + kt * 32;
#pragma unroll
                for (int h = 0; h < 4; ++h) {
                    float4 b0 = *(const float4*)(src + h * 8);
                    float4 b1 = *(const float4*)(src + h * 8 + 4);
                    short8 hv;
                    hv[0] = (short)f2bf(b0.x); hv[1] = (short)f2bf(b0.y);
                    hv[2] = (short)f2bf(b0.z); hv[3] = (short)f2bf(b0.w);
                    hv[4] = (short)f2bf(b1.x); hv[5] = (short)f2bf(b1.y);
                    hv[6] = (short)f2bf(b1.z); hv[7] = (short)f2bf(b1.w);
                    *(short8*)&B_s[tid][h * 8] = hv;
                }
            }
            __syncthreads();
            short8 af[4], bf[4];
#pragma unroll
            for (int mt = 0; mt < 4; ++mt)
                af[mt] = *(const short8*)&A_s[mt * 16 + l15][quad * 8];
#pragma unroll
            for (int nt = 0; nt < 4; ++nt)
                bf[nt] = *(const short8*)&B_s[wave * 64 + nt * 16 + l15][quad * 8];
#pragma unroll
            for (int mt = 0; mt < 4; ++mt)
#pragma unroll
                for (int nt = 0; nt < 4; ++nt)
                    acc[mt][nt] = __builtin_amdgcn_mfma_f32_16x16x32_bf16(
                        af[mt], bf[nt], acc[mt][nt], 0, 0, 0);
        }
        // write scores to Csub:  row = token, col = cand-in-tile
        __syncthreads();
#pragma unroll
        for (int mt = 0; mt < 4; ++mt)
#pragma unroll
            for (int nt = 0; nt < 4; ++nt)
#pragma unroll
                for (int r = 0; r < 4; ++r)
                    Csub[mt * 16 + quad * 4 + r][wave * 64 + nt * 16 + l15] =
                        __float2half(acc[mt][nt][r]);
        __syncthreads();
        // streaming top-window scan (owner threads)
        for (int j = 0; j < 64; ++j) {
            const int c = opart * 64 + j;
            const float a = __half2float(Csub[otok][c]);
            if (a > submax) submax = a;
            if (a >= submax - TAU_A) {
                const int gc = ct * 256 + c;
                if (scnt < 4) { sval[scnt] = a; sidx[scnt] = gc; ++scnt; }
                else {
                    int w = 0;
#pragma unroll
                    for (int s = 1; s < 4; ++s) if (sval[s] < sval[w]) w = s;
                    if (a > sval[w]) { sval[w] = a; sidx[w] = gc; }
                }
            }
        }
    }

    // merge the 4 sub-owners of each token into a job list
    mgMax[otok][opart] = submax;
#pragma unroll
    for (int s = 0; s < 4; ++s) {
        mgVal[otok][opart][s] = (s < scnt) ? sval[s] : -3.0e38f;
        mgIdx[otok][opart][s] = sidx[s];
    }
    __syncthreads();
    if (tid < 64) {
        float g = mgMax[tid][0];
#pragma unroll
        for (int p = 1; p < 4; ++p) g = fmaxf(g, mgMax[tid][p]);
        int cnt = 0;
#pragma unroll
        for (int p = 0; p < 4; ++p)
#pragma unroll
            for (int s = 0; s < 4; ++s) {
                const float a = mgVal[tid][p][s];
                if (a >= g - TAU_A && cnt < 8) jobIdx[tid][cnt++] = mgIdx[tid][p][s];
            }
        jobCnt[tid] = cnt;
    }
    __syncthreads();

    // ---- rescue: exact fp64 rescoring with round-2's fp32-grid emulation ----
    double lsum = 0.0;
    for (int t = wave; t < 64; t += 4) {
        const float* fr = feat + (size_t)(row0 + t) * DIM + lane * 8;
        float4 f0 = *(const float4*)fr;
        float4 f1 = *(const float4*)(fr + 4);
        if (RESID) {
            const float* pr = cb_prev + (size_t)sPrev[t] * DIM + lane * 8;
            float4 p0 = *(const float4*)pr;
            float4 p1 = *(const float4*)(pr + 4);
            f0.x -= p0.x; f0.y -= p0.y; f0.z -= p0.z; f0.w -= p0.w;
            f1.x -= p1.x; f1.y -= p1.y; f1.z -= p1.z; f1.w -= p1.w;
        }
        float v[8] = {f0.x, f0.y, f0.z, f0.w, f1.x, f1.y, f1.z, f1.w};
        double vv = 0.0;
#pragma unroll
        for (int u = 0; u < 8; ++u) vv += (double)v[u] * (double)v[u];
        for (int o = 1; o < 64; o <<= 1) vv += __shfl_xor(vv, o, 64);

        float bestd = 3.4e38f; int besti = 0x7fffffff; double bestl = 0.0;
        const int cnt = jobCnt[t];
        for (int j = 0; j < cnt; ++j) {
            const int c = jobIdx[t][j];
            const float* cr = cb + (size_t)c * DIM + lane * 8;
            float4 c0v = *(const float4*)cr;
            float4 c1v = *(const float4*)(cr + 4);
            float cv[8] = {c0v.x, c0v.y, c0v.z, c0v.w, c1v.x, c1v.y, c1v.z, c1v.w};
            double dot = 0.0, cn = 0.0;
#pragma unroll
            for (int u = 0; u < 8; ++u) {
                dot += (double)v[u] * (double)cv[u];
                cn  += (double)cv[u] * (double)cv[u];
            }
            for (int o = 1; o < 64; o <<= 1) {
                dot += __shfl_xor(dot, o, 64);
                cn  += __shfl_xor(cn,  o, 64);
            }
            const float A32 = (float)vv;
            const float d32 = __fsub_rn(__fadd_rn(A32, (float)cn),
                                        __fmul_rn(2.0f, (float)dot));
            if (d32 < bestd || (d32 == bestd && c < besti)) {
                bestd = d32; besti = c; bestl = (vv + cn) - 2.0 * dot;
            }
        }
        if (lane == 0) { idx_out[row0 + t] = (float)besti; lsum += bestl; }
    }
    if (lane == 0) atomicAdd(loss_acc, (float)lsum);
}

// ======================= out: bf16 MFMA gather-GEMM ========================
__global__ __launch_bounds__(256)
void out_kernel(const float* __restrict__ t_cb, const float* __restrict__ e_cb,
                const float* __restrict__ d_cb0, const float* __restrict__ d_cb1,
                const float* __restrict__ W, const float* __restrict__ bias,
                const float* __restrict__ idx_base, float* __restrict__ outq) {
    __shared__ __align__(16) ushort A_s[128][40];
    __shared__ __align__(16) ushort B_s[128][40];
    __shared__ int sIdx[4][128];

    const int tid  = threadIdx.x;
    const int lane = tid & 63;
    const int wave = tid >> 6;
    const int quad = lane >> 4;
    const int l15  = lane & 15;
    const int row0 = blockIdx.x * 128;
    const int col0 = blockIdx.y * 128;
    const int mw = (wave >> 1) * 64, nw = (wave & 1) * 64;

    {
        int e = tid;
        sIdx[e >> 7][e & 127] = (int)idx_base[(size_t)(e >> 7) * NTOK + row0 + (e & 127)];
        e = tid + 256;
        sIdx[e >> 7][e & 127] = (int)idx_base[(size_t)(e >> 7) * NTOK + row0 + (e & 127)];
    }

    float4v acc[4][4];
#pragma unroll
    for (int mt = 0; mt < 4; ++mt)
#pragma unroll
        for (int nt = 0; nt < 4; ++nt) acc[mt][nt] = 0.0f;

    for (int kt = 0; kt < NDIM3 / 32; ++kt) {
        const int k0 = kt * 32;
        const int seg = k0 >> 9;
        __syncthreads();
        {   // A: gathered combined row -> bf16
            const int tok = tid >> 1, kk = (tid & 1) * 16;
            const int off = (k0 & 511) + kk;
            float fv[16];
            if (seg == 0) {
                const float* s = t_cb + (size_t)sIdx[0][tok] * DIM + off;
#pragma unroll
                for (int u = 0; u < 4; ++u) *(float4*)&fv[u * 4] = *(const float4*)(s + u * 4);
            } else if (seg == 1) {
                const float* s = e_cb + (size_t)sIdx[1][tok] * DIM + off;
#pragma unroll
                for (int u = 0; u < 4; ++u) *(float4*)&fv[u * 4] = *(const float4*)(s + u * 4);
            } else {
                const float* s0 = d_cb0 + (size_t)sIdx[2][tok] * DIM + off;
                const float* s1 = d_cb1 + (size_t)sIdx[3][tok] * DIM + off;
#pragma unroll
                for (int u = 0; u < 4; ++u) {
                    float4 a0 = *(const float4*)(s0 + u * 4);
                    float4 a1 = *(const float4*)(s1 + u * 4);
                    fv[u * 4 + 0] = a0.x + a1.x; fv[u * 4 + 1] = a0.y + a1.y;
                    fv[u * 4 + 2] = a0.z + a1.z; fv[u * 4 + 3] = a0.w + a1.w;
                }
            }
#pragma unroll
            for (int h = 0; h < 2; ++h) {
                short8 hv;
#pragma unroll
                for (int u = 0; u < 8; ++u) hv[u] = (short)f2bf(fv[h * 8 + u]);
                *(short8*)&A_s[tok][kk + h * 8] = hv;
            }
        }
        {   // B: out_W rows
            const int col = tid >> 1, kk = (tid & 1) * 16;
            const float* s = W + (size_t)(col0 + col) * NDIM3 + k0 + kk;
#pragma unroll
            for (int h = 0; h < 2; ++h) {
                float4 b0 = *(const float4*)(s + h * 8);
                float4 b1 = *(const float4*)(s + h * 8 + 4);
                short8 hv;
                hv[0] = (short)f2bf(b0.x); hv[1] = (short)f2bf(b0.y);
                hv[2] = (short)f2bf(b0.z); hv[3] = (short)f2bf(b0.w);
                hv[4] = (short)f2bf(b1.x); hv[5] = (short)f2bf(b1.y);
                hv[6] = (short)f2bf(b1.z); hv[7] = (short)f2bf(b1.w);
                *(short8*)&B_s[col][kk + h * 8] = hv;
            }
        }
        __syncthreads();
        short8 af[4], bf[4];
#pragma unroll
        for (int mt = 0; mt < 4; ++mt)
            af[mt] = *(const short8*)&A_s[mw + mt * 16 + l15][quad * 8];
#pragma unroll
        for (int nt = 0; nt < 4; ++nt)
            bf[nt] = *(const short8*)&B_s[nw + nt * 16 + l15][quad * 8];
#pragma unroll
        for (int mt = 0; mt < 4; ++mt)
#pragma unroll
            for (int nt = 0; nt < 4; ++nt)
                acc[mt][nt] = __builtin_amdgcn_mfma_f32_16x16x32_bf16(
                    af[mt], bf[nt], acc[mt][nt], 0, 0, 0);
    }

#pragma unroll
    for (int nt = 0; nt < 4; ++nt) {
        const int col = col0 + nw + nt * 16 + l15;
        const float bc = bias[col];
#pragma unroll
        for (int mt = 0; mt < 4; ++mt) {
            const int row = row0 + mw + mt * 16 + quad * 4;
#pragma unroll
            for (int r = 0; r < 4; ++r)
                outq[(size_t)(row + r) * DIM + col] = acc[mt][nt][r] + bc;
        }
    }
}

// ---------------------------------------------------------------------------
__global__ void init_loss_kernel(float* __restrict__ p) { *p = 0.0f; }

__global__ void finalize_kernel(float* __restrict__ p) {
    *p = 1.25f * (*p) / (float)(NTOK * DIM);
}

// ---------------------------------------------------------------------------
extern "C" void kernel_launch(void* const* d_in, const int* in_sizes, int n_in,
                              void* d_out, int out_size, void* d_ws, size_t ws_size,
                              hipStream_t stream) {
    const float* x    = (const float*)d_in[0];
    const float* tW   = (const float*)d_in[1];
    const float* tb   = (const float*)d_in[2];
    const float* eW   = (const float*)d_in[3];
    const float* eb   = (const float*)d_in[4];
    const float* dW   = (const float*)d_in[5];
    const float* db   = (const float*)d_in[6];
    const float* oW   = (const float*)d_in[7];
    const float* ob   = (const float*)d_in[8];
    const float* t_cb = (const float*)d_in[9];
    const float* e_cb = (const float*)d_in[10];
    const float* c0   = (const float*)d_in[11];
    const float* c1   = (const float*)d_in[12];

    float* out = (float*)d_out;
    float* feat = out;                          // feat scratch, overwritten at end
    float* idx_t = out + (size_t)NTOK * DIM;
    float* idx_e = idx_t + NTOK;
    float* idx_0 = idx_e + NTOK;
    float* idx_1 = idx_0 + NTOK;
    float* loss_out = idx_1 + NTOK;

    const dim3 gproj(NTOK / PBM, DIM / PBN);    // (1024, 4)
    const int  gvq = NTOK / 64;                 // 1024
    const dim3 gout(NTOK / 128, DIM / 128);     // (512, 4)

    init_loss_kernel<<<1, 1, 0, stream>>>(loss_out);

    proj_kernel<<<gproj, 256, 0, stream>>>(x, tW, tb, feat);
    vq_fused<false><<<gvq, 256, 0, stream>>>(feat, t_cb, 512, nullptr, nullptr, idx_t, loss_out);

    proj_kernel<<<gproj, 256, 0, stream>>>(x, eW, eb, feat);
    vq_fused<false><<<gvq, 256, 0, stream>>>(feat, e_cb, 256, nullptr, nullptr, idx_e, loss_out);

    proj_kernel<<<gproj, 256, 0, stream>>>(x, dW, db, feat);
    vq_fused<false><<<gvq, 256, 0, stream>>>(feat, c0, 512, nullptr, nullptr, idx_0, loss_out);
    vq_fused<true><<<gvq, 256, 0, stream>>>(feat, c1, 512, c0, idx_0, idx_1, loss_out);

    out_kernel<<<gout, 256, 0, stream>>>(t_cb, e_cb, c0, c1, oW, ob, idx_t, out);
    finalize_kernel<<<1, 1, 0, stream>>>(loss_out);
}